// Round 1
// baseline (1296.944 us; speedup 1.0000x reference)
//
#include <hip/hip_runtime.h>
#include <stdint.h>

typedef unsigned short ushort_t;
typedef unsigned int u32;
typedef short bf16x8 __attribute__((ext_vector_type(8)));
typedef float f32x4 __attribute__((ext_vector_type(4)));

#define MFMA16(a, b, c) __builtin_amdgcn_mfma_f32_16x16x32_bf16((a), (b), (c), 0, 0, 0)

__device__ __forceinline__ ushort_t f2bf(float f) {
  union { float f; u32 u; } v; v.f = f;
  return (ushort_t)((v.u + 0x7FFFu + ((v.u >> 16) & 1u)) >> 16);
}
__device__ __forceinline__ float bf2f(ushort_t h) {
  union { u32 u; float f; } v; v.u = ((u32)h) << 16;
  return v.f;
}

// Store one Q/K value into A/B-fragment-packed layout for mfma_f32_16x16x32_bf16.
// Frag covers 16 rows x 32 d. lane = (row&15) | (((d>>3)&3)<<4), j = d&7.
// Layout: [hb][t/16][d/32][lane][8]
__device__ __forceinline__ void store_qk(ushort_t* __restrict__ hi_arr, ushort_t* __restrict__ lo_arr,
                                         int hb, int t, int d, float v) {
  int lane = (t & 15) | (((d >> 3) & 3) << 4);
  size_t addr = ((((size_t)hb * 128 + (t >> 4)) * 8 + (d >> 5)) << 9) + ((size_t)lane << 3) + (d & 7);
  ushort_t h = f2bf(v);
  ushort_t l = f2bf(v - bf2f(h));
  hi_arr[addr] = h;
  lo_arr[addr] = l;
}

// ---------------- K1: QKV projection + PReLU + LayerNorm(channel) ----------------
__global__ __launch_bounds__(256) void k_proj_qkv(
    const float* __restrict__ x,
    const float* __restrict__ Wq, const float* __restrict__ bq, const float* __restrict__ aq,
    const float* __restrict__ gq, const float* __restrict__ beq,
    const float* __restrict__ Wk, const float* __restrict__ bk, const float* __restrict__ ak,
    const float* __restrict__ gk, const float* __restrict__ bek,
    const float* __restrict__ Wv, const float* __restrict__ bv, const float* __restrict__ av,
    const float* __restrict__ gv, const float* __restrict__ bev,
    ushort_t* __restrict__ Qp_hi, ushort_t* __restrict__ Qp_lo,
    ushort_t* __restrict__ Kp_hi, ushort_t* __restrict__ Kp_lo,
    ushort_t* __restrict__ Vhi, ushort_t* __restrict__ Vlo)
{
  int tid = blockIdx.x * 256 + threadIdx.x;
  int f = tid & 63;
  int t = (tid >> 6) & 2047;
  int b = tid >> 17;

  float qa[16], ka[16], va[64];
#pragma unroll
  for (int o = 0; o < 16; ++o) { qa[o] = bq[o]; ka[o] = bk[o]; }
#pragma unroll
  for (int o = 0; o < 64; ++o) va[o] = bv[o];

  const float* xp = x + ((size_t)b * 64 * 2048 + t) * 64 + f;
  for (int c = 0; c < 64; ++c) {
    float xv = xp[(size_t)c * (2048 * 64)];
#pragma unroll
    for (int o = 0; o < 16; ++o) qa[o] += Wq[o * 64 + c] * xv;
#pragma unroll
    for (int o = 0; o < 16; ++o) ka[o] += Wk[o * 64 + c] * xv;
#pragma unroll
    for (int o = 0; o < 64; ++o) va[o] += Wv[o * 64 + c] * xv;
  }

#pragma unroll
  for (int h = 0; h < 4; ++h) {
    int hb = h * 2 + b;
    // Q: PReLU + LN(4) + affine; fold attention scale 1/sqrt(256) = 1/16 (exact pow2)
    {
      float aa = aq[h];
      float y[4]; float mu = 0.f;
#pragma unroll
      for (int j = 0; j < 4; ++j) { float u = qa[h * 4 + j]; u = u >= 0.f ? u : aa * u; y[j] = u; mu += u; }
      mu *= 0.25f;
      float var = 0.f;
#pragma unroll
      for (int j = 0; j < 4; ++j) { float d = y[j] - mu; var += d * d; }
      float is = rsqrtf(var * 0.25f + 1e-5f);
#pragma unroll
      for (int j = 0; j < 4; ++j) {
        float v = ((y[j] - mu) * is * gq[h * 4 + j] + beq[h * 4 + j]) * 0.0625f;
        store_qk(Qp_hi, Qp_lo, hb, t, j * 64 + f, v);
      }
    }
    // K: PReLU + LN(4) + affine
    {
      float aa = ak[h];
      float y[4]; float mu = 0.f;
#pragma unroll
      for (int j = 0; j < 4; ++j) { float u = ka[h * 4 + j]; u = u >= 0.f ? u : aa * u; y[j] = u; mu += u; }
      mu *= 0.25f;
      float var = 0.f;
#pragma unroll
      for (int j = 0; j < 4; ++j) { float d = y[j] - mu; var += d * d; }
      float is = rsqrtf(var * 0.25f + 1e-5f);
#pragma unroll
      for (int j = 0; j < 4; ++j) {
        float v = (y[j] - mu) * is * gk[h * 4 + j] + bek[h * 4 + j];
        store_qk(Kp_hi, Kp_lo, hb, t, j * 64 + f, v);
      }
    }
    // V: PReLU + LN(16) + affine, plain [hb][t][dv] layout (packed later)
    {
      float aa = av[h];
      float y[16]; float mu = 0.f;
#pragma unroll
      for (int j = 0; j < 16; ++j) { float u = va[h * 16 + j]; u = u >= 0.f ? u : aa * u; y[j] = u; mu += u; }
      mu *= 0.0625f;
      float var = 0.f;
#pragma unroll
      for (int j = 0; j < 16; ++j) { float d = y[j] - mu; var += d * d; }
      float is = rsqrtf(var * 0.0625f + 1e-5f);
#pragma unroll
      for (int j = 0; j < 16; ++j) {
        float v = (y[j] - mu) * is * gv[h * 16 + j] + bev[h * 16 + j];
        size_t addr = ((size_t)hb * 2048 + t) * 1024 + j * 64 + f;
        ushort_t hh = f2bf(v);
        Vhi[addr] = hh;
        Vlo[addr] = f2bf(v - bf2f(hh));
      }
    }
  }
}

// ---------------- K2: pack V into PV B-fragment layout ----------------
// B-frag (16x16x32): lane holds V[ts = tsblk*32 + (lane>>4)*8 + j][dv = dvt*16 + (lane&15)]
// Layout: [hb][t/32][dv/16][lane][8]
__global__ __launch_bounds__(256) void k_vpack(
    const ushort_t* __restrict__ Vhi, const ushort_t* __restrict__ Vlo,
    ushort_t* __restrict__ Vp_hi, ushort_t* __restrict__ Vp_lo)
{
  int bid = blockIdx.x;
  int dvgrp = bid & 15;
  int tsblk = (bid >> 4) & 63;
  int hb = bid >> 10;
  int lane = threadIdx.x & 63;
  int dvt = dvgrp * 4 + (threadIdx.x >> 6);
  int dv = dvt * 16 + (lane & 15);
  int tbase = tsblk * 32 + ((lane >> 4) << 3);

  union { ushort_t s[8]; uint4 v; } hbuf, lbuf;
#pragma unroll
  for (int j = 0; j < 8; ++j) {
    size_t src = ((size_t)hb * 2048 + tbase + j) * 1024 + dv;
    hbuf.s[j] = Vhi[src];
    lbuf.s[j] = Vlo[src];
  }
  size_t dst = ((((size_t)hb * 64 + tsblk) * 64 + dvt) << 9) + ((size_t)lane << 3);
  *(uint4*)(Vp_hi + dst) = hbuf.v;
  *(uint4*)(Vp_lo + dst) = lbuf.v;
}

// ---------------- K3: flash attention, bf16x3, 8 waves / 64 q-rows / full dv ----------------
__global__ __launch_bounds__(512, 2) void k_attn(
    const ushort_t* __restrict__ Qp_hi, const ushort_t* __restrict__ Qp_lo,
    const ushort_t* __restrict__ Kp_hi, const ushort_t* __restrict__ Kp_lo,
    const ushort_t* __restrict__ Vp_hi, const ushort_t* __restrict__ Vp_lo,
    float* __restrict__ O)
{
  extern __shared__ char smem[];
  ushort_t* K_lds   = (ushort_t*)(smem);            // [hi/lo][16 chunks][512] : 32KB
  ushort_t* V_lds   = (ushort_t*)(smem + 32768);    // [64 frags][512]        : 64KB
  ushort_t* Qlo_lds = (ushort_t*)(smem + 98304);    // [4 qblk][8 kk][512]    : 32KB
  ushort_t* P_lds   = (ushort_t*)(smem + 131072);   // [4 qblk][hi/lo][512]   : 8KB
  float*    pmax    = (float*)(smem + 139264);      // [2][64]
  float*    psum    = (float*)(smem + 139776);      // [2][64]

  int lane = threadIdx.x & 63;
  int wid  = threadIdx.x >> 6;
  int qblk = wid >> 1;   // 16-row block within the 64-row q-tile
  int half = wid & 1;    // S: ts-half; PV: dv-half
  int hb = blockIdx.x & 7;        // hb -> XCD (round-robin dispatch)
  int qtile = blockIdx.x >> 3;
  int tbase4 = (lane >> 4) << 2;

  // Q-hi fragments in registers (reused for all 64 s-tiles)
  bf16x8 qh[8];
  {
    const ushort_t* qsrc = Qp_hi + (((size_t)hb * 128 + qtile * 4 + qblk) << 12) + ((size_t)lane << 3);
#pragma unroll
    for (int kk = 0; kk < 8; ++kk) qh[kk] = *(const bf16x8*)(qsrc + ((size_t)kk << 9));
  }
  // Stage Q-lo (32KB) into LDS
  {
    const ushort_t* src = Qp_lo + (((size_t)hb * 128 + qtile * 4) << 12) + ((size_t)lane << 3);
#pragma unroll
    for (int i = 0; i < 4; ++i) {
      int c = wid * 4 + i;
      *(uint4*)(Qlo_lds + ((size_t)c << 9) + ((size_t)lane << 3)) = *(const uint4*)(src + ((size_t)c << 9));
    }
  }

  f32x4 acc[32];
#pragma unroll
  for (int i = 0; i < 32; ++i) acc[i] = (f32x4){0.f, 0.f, 0.f, 0.f};
  float m_run[4] = {-1e30f, -1e30f, -1e30f, -1e30f};
  float l_run[4] = {0.f, 0.f, 0.f, 0.f};

  for (int s = 0; s < 64; ++s) {
    __syncthreads();  // previous tile fully consumed
    // Stage K hi+lo (32KB) + V hi (64KB): 96 x 1KB chunks, 12 per wave
    {
      const ushort_t* khsrc = Kp_hi + (((size_t)hb * 128 + 2 * s) << 12);
      const ushort_t* klsrc = Kp_lo + (((size_t)hb * 128 + 2 * s) << 12);
      const ushort_t* vhsrc = Vp_hi + (((size_t)hb * 64 + s) << 15);
#pragma unroll
      for (int i = 0; i < 12; ++i) {
        int gc = wid * 12 + i;
        const ushort_t* srcp;
        ushort_t* dstp;
        if (gc < 16)      { srcp = khsrc + ((size_t)gc << 9);        dstp = K_lds + ((size_t)gc << 9); }
        else if (gc < 32) { srcp = klsrc + ((size_t)(gc - 16) << 9); dstp = K_lds + 8192 + ((size_t)(gc - 16) << 9); }
        else              { srcp = vhsrc + ((size_t)(gc - 32) << 9); dstp = V_lds + ((size_t)(gc - 32) << 9); }
        *(uint4*)(dstp + ((size_t)lane << 3)) = *(const uint4*)(srcp + ((size_t)lane << 3));
      }
    }
    __syncthreads();

    // S = (Q/16)·K^T for our 16x16 tile, bf16x3
    f32x4 sacc = (f32x4){0.f, 0.f, 0.f, 0.f};
#pragma unroll
    for (int kk = 0; kk < 8; ++kk) {
      bf16x8 bh  = *(const bf16x8*)(K_lds + (((size_t)(half * 8 + kk)) << 9) + ((size_t)lane << 3));
      bf16x8 bl  = *(const bf16x8*)(K_lds + 8192 + (((size_t)(half * 8 + kk)) << 9) + ((size_t)lane << 3));
      bf16x8 qlf = *(const bf16x8*)(Qlo_lds + (((size_t)(qblk * 8 + kk)) << 9) + ((size_t)lane << 3));
      sacc = MFMA16(qh[kk], bh, sacc);
      sacc = MFMA16(qh[kk], bl, sacc);
      sacc = MFMA16(qlf, bh, sacc);
    }

    // partial row-max across our 16 cols (lanes sharing lane>>4 hold same rows)
    float rm[4];
#pragma unroll
    for (int r = 0; r < 4; ++r) rm[r] = sacc[r];
#pragma unroll
    for (int m = 1; m <= 8; m <<= 1) {
#pragma unroll
      for (int r = 0; r < 4; ++r) rm[r] = fmaxf(rm[r], __shfl_xor(rm[r], m));
    }
    if ((lane & 15) == 0)
      *(f32x4*)&pmax[half * 64 + qblk * 16 + tbase4] = (f32x4){rm[0], rm[1], rm[2], rm[3]};
    __syncthreads();

    f32x4 p0 = *(const f32x4*)&pmax[qblk * 16 + tbase4];
    f32x4 p1 = *(const f32x4*)&pmax[64 + qblk * 16 + tbase4];
    float rs[4], pv_[4];
#pragma unroll
    for (int r = 0; r < 4; ++r) {
      float mnew = fmaxf(m_run[r], fmaxf(p0[r], p1[r]));
      rs[r] = __expf(m_run[r] - mnew);
      m_run[r] = mnew;
      pv_[r] = __expf(sacc[r] - mnew);
    }
    // partial row-sum
    float ps[4];
#pragma unroll
    for (int r = 0; r < 4; ++r) ps[r] = pv_[r];
#pragma unroll
    for (int m = 1; m <= 8; m <<= 1) {
#pragma unroll
      for (int r = 0; r < 4; ++r) ps[r] += __shfl_xor(ps[r], m);
    }
    if ((lane & 15) == 0)
      *(f32x4*)&psum[half * 64 + qblk * 16 + tbase4] = (f32x4){ps[0], ps[1], ps[2], ps[3]};

    // write P (hi/lo) into PV A-frag layout: idx = tgt*8 + (ts&7), tgt = (row%16) | ((ts>>3)<<4)
    {
      int ts = half * 16 + (lane & 15);
      int col_sel = (ts >> 3) << 4;
      int jj = ts & 7;
#pragma unroll
      for (int r = 0; r < 4; ++r) {
        int tgt = (tbase4 + r) | col_sel;
        ushort_t ph = f2bf(pv_[r]);
        ushort_t pl = f2bf(pv_[r] - bf2f(ph));
        P_lds[(((size_t)(qblk * 2 + 0)) << 9) + (tgt << 3) + jj] = ph;
        P_lds[(((size_t)(qblk * 2 + 1)) << 9) + (tgt << 3) + jj] = pl;
      }
    }
    // rescale O accumulator
#pragma unroll
    for (int i = 0; i < 32; ++i) {
#pragma unroll
      for (int r = 0; r < 4; ++r) acc[i][r] *= rs[r];
    }
    __syncthreads();  // P_lds + psum visible

    {
      f32x4 s0 = *(const f32x4*)&psum[qblk * 16 + tbase4];
      f32x4 s1 = *(const f32x4*)&psum[64 + qblk * 16 + tbase4];
#pragma unroll
      for (int r = 0; r < 4; ++r) l_run[r] = l_run[r] * rs[r] + s0[r] + s1[r];
    }

    // PV: acc += P · V (bf16x3); V-hi from LDS, V-lo streamed from global frag-packed
    {
      bf16x8 pAh = *(const bf16x8*)(P_lds + (((size_t)(qblk * 2 + 0)) << 9) + ((size_t)lane << 3));
      bf16x8 pAl = *(const bf16x8*)(P_lds + (((size_t)(qblk * 2 + 1)) << 9) + ((size_t)lane << 3));
      const ushort_t* vlsrc = Vp_lo + (((size_t)hb * 64 + s) << 15) + (((size_t)(half * 32)) << 9) + ((size_t)lane << 3);
#pragma unroll
      for (int i = 0; i < 32; ++i) {
        bf16x8 vh = *(const bf16x8*)(V_lds + (((size_t)(half * 32 + i)) << 9) + ((size_t)lane << 3));
        bf16x8 vl = *(const bf16x8*)(vlsrc + ((size_t)i << 9));
        acc[i] = MFMA16(pAh, vh, acc[i]);
        acc[i] = MFMA16(pAl, vh, acc[i]);
        acc[i] = MFMA16(pAh, vl, acc[i]);
      }
    }
  }

  // epilogue: normalize and write O in [B][C=64][T][F=64] fp32
  float inv_[4];
#pragma unroll
  for (int r = 0; r < 4; ++r) inv_[r] = 1.0f / l_run[r];
  int h = hb >> 1, b = hb & 1;
  int trow = qtile * 64 + qblk * 16 + tbase4;
#pragma unroll
  for (int i = 0; i < 32; ++i) {
    int dv = half * 512 + i * 16 + (lane & 15);
    float* op = O + (((size_t)b * 64 + h * 16 + (dv >> 6)) * 2048 + trow) * 64 + (dv & 63);
#pragma unroll
    for (int r = 0; r < 4; ++r) op[(size_t)r * 64] = acc[i][r] * inv_[r];
  }
}

// ---------------- K4: output projection + PReLU + LN(64) + residual ----------------
__global__ __launch_bounds__(256) void k_outproj(
    const float* __restrict__ O, const float* __restrict__ Wp, const float* __restrict__ bp,
    const float* __restrict__ ap, const float* __restrict__ gp, const float* __restrict__ bep,
    const float* __restrict__ x, float* __restrict__ out)
{
  int tid = blockIdx.x * 256 + threadIdx.x;
  int f = tid & 63;
  int t = (tid >> 6) & 2047;
  int b = tid >> 17;

  float acc[64];
#pragma unroll
  for (int o = 0; o < 64; ++o) acc[o] = bp[o];
  const float* op_ = O + ((size_t)b * 64 * 2048 + t) * 64 + f;
  for (int c = 0; c < 64; ++c) {
    float ov = op_[(size_t)c * (2048 * 64)];
#pragma unroll
    for (int o = 0; o < 64; ++o) acc[o] += Wp[o * 64 + c] * ov;
  }
  float aa = ap[0];
  float mu = 0.f;
#pragma unroll
  for (int o = 0; o < 64; ++o) { float y = acc[o]; y = y >= 0.f ? y : aa * y; acc[o] = y; mu += y; }
  mu *= 0.015625f;
  float var = 0.f;
#pragma unroll
  for (int o = 0; o < 64; ++o) { float d = acc[o] - mu; var += d * d; }
  float is = rsqrtf(var * 0.015625f + 1e-5f);
  size_t base = ((size_t)b * 64 * 2048 + t) * 64 + f;
#pragma unroll
  for (int o = 0; o < 64; ++o) {
    size_t idx = base + (size_t)o * (2048 * 64);
    out[idx] = (acc[o] - mu) * is * gp[o] + bep[o] + x[idx];
  }
}

extern "C" void kernel_launch(void* const* d_in, const int* in_sizes, int n_in,
                              void* d_out, int out_size, void* d_ws, size_t ws_size,
                              hipStream_t stream) {
  (void)in_sizes; (void)n_in; (void)out_size; (void)ws_size;
  const float* x   = (const float*)d_in[0];
  const float* Wq  = (const float*)d_in[1];
  const float* bq  = (const float*)d_in[2];
  const float* aq  = (const float*)d_in[3];
  const float* gq  = (const float*)d_in[4];
  const float* beq = (const float*)d_in[5];
  const float* Wk  = (const float*)d_in[6];
  const float* bk  = (const float*)d_in[7];
  const float* ak  = (const float*)d_in[8];
  const float* gk  = (const float*)d_in[9];
  const float* bek = (const float*)d_in[10];
  const float* Wv  = (const float*)d_in[11];
  const float* bv  = (const float*)d_in[12];
  const float* av  = (const float*)d_in[13];
  const float* gv  = (const float*)d_in[14];
  const float* bev = (const float*)d_in[15];
  const float* Wp  = (const float*)d_in[16];
  const float* bp  = (const float*)d_in[17];
  const float* ap  = (const float*)d_in[18];
  const float* gp  = (const float*)d_in[19];
  const float* bep = (const float*)d_in[20];

  char* ws = (char*)d_ws;
  const size_t MB = 1024 * 1024;
  ushort_t* Qp_hi = (ushort_t*)(ws + 0 * MB);    // 8MB  [8][128][8][64][8]
  ushort_t* Qp_lo = (ushort_t*)(ws + 8 * MB);    // 8MB
  ushort_t* Kp_hi = (ushort_t*)(ws + 16 * MB);   // 8MB
  ushort_t* Kp_lo = (ushort_t*)(ws + 24 * MB);   // 8MB
  ushort_t* Vhi   = (ushort_t*)(ws + 32 * MB);   // 32MB [8][2048][1024]
  ushort_t* Vlo   = (ushort_t*)(ws + 64 * MB);   // 32MB
  ushort_t* Vp_hi = (ushort_t*)(ws + 96 * MB);   // 32MB [8][64][64][64][8]
  ushort_t* Vp_lo = (ushort_t*)(ws + 128 * MB);  // 32MB
  float*    Obuf  = (float*)(ws + 32 * MB);      // 64MB, aliases Vhi/Vlo (dead after k_vpack)

  hipFuncSetAttribute((const void*)k_attn, hipFuncAttributeMaxDynamicSharedMemorySize, 140288);

  k_proj_qkv<<<1024, 256, 0, stream>>>(x, Wq, bq, aq, gq, beq, Wk, bk, ak, gk, bek,
                                       Wv, bv, av, gv, bev,
                                       Qp_hi, Qp_lo, Kp_hi, Kp_lo, Vhi, Vlo);
  k_vpack<<<8192, 256, 0, stream>>>(Vhi, Vlo, Vp_hi, Vp_lo);
  k_attn<<<256, 512, 140288, stream>>>(Qp_hi, Qp_lo, Kp_hi, Kp_lo, Vp_hi, Vp_lo, Obuf);
  k_outproj<<<1024, 256, 0, stream>>>(Obuf, Wp, bp, ap, gp, bep, x, (float*)d_out);
}

// Round 4
// 555.614 us; speedup vs baseline: 2.3343x; 2.3343x over previous
//
#include <hip/hip_runtime.h>
#include <stdint.h>

typedef unsigned short ushort_t;
typedef unsigned int u32;
typedef short bf16x8 __attribute__((ext_vector_type(8)));
typedef float f32x4 __attribute__((ext_vector_type(4)));

#define MFMA16(a, b, c) __builtin_amdgcn_mfma_f32_16x16x32_bf16((a), (b), (c), 0, 0, 0)

__device__ __forceinline__ ushort_t f2bf(float f) {
  union { float f; u32 u; } v; v.f = f;
  return (ushort_t)((v.u + 0x7FFFu + ((v.u >> 16) & 1u)) >> 16);
}
__device__ __forceinline__ float bf2f(ushort_t h) {
  union { u32 u; float f; } v; v.u = ((u32)h) << 16;
  return v.f;
}

// Q/K fragment store for mfma_f32_16x16x32_bf16 (A: m=t,k=d | B: n=ts,k=d).
// Layout: [hb][t/16][d/32][lane][8]   (validated in R1)
__device__ __forceinline__ void store_frag(ushort_t* __restrict__ arr, int hb, int t, int d, float v) {
  int lane = (t & 15) | (((d >> 3) & 3) << 4);
  size_t addr = ((((size_t)hb * 128 + (t >> 4)) * 8 + (d >> 5)) << 9) + ((size_t)lane << 3) + (d & 7);
  arr[addr] = f2bf(v);
}

// ---------------- K1: QKV projection + PReLU + LayerNorm(channel) ----------------
__global__ __launch_bounds__(256) void k_proj_qkv(
    const float* __restrict__ x,
    const float* __restrict__ Wq, const float* __restrict__ bq, const float* __restrict__ aq,
    const float* __restrict__ gq, const float* __restrict__ beq,
    const float* __restrict__ Wk, const float* __restrict__ bk, const float* __restrict__ ak,
    const float* __restrict__ gk, const float* __restrict__ bek,
    const float* __restrict__ Wv, const float* __restrict__ bv, const float* __restrict__ av,
    const float* __restrict__ gv, const float* __restrict__ bev,
    ushort_t* __restrict__ Qp, ushort_t* __restrict__ Kp,
    ushort_t* __restrict__ Vp_hi, ushort_t* __restrict__ Vp_lo)
{
  int tid = blockIdx.x * 256 + threadIdx.x;
  int f = tid & 63;
  int t = (tid >> 6) & 2047;
  int b = tid >> 17;

  float qa[16], ka[16], va[64];
#pragma unroll
  for (int o = 0; o < 16; ++o) { qa[o] = bq[o]; ka[o] = bk[o]; }
#pragma unroll
  for (int o = 0; o < 64; ++o) va[o] = bv[o];

  const float* xp = x + ((size_t)b * 64 * 2048 + t) * 64 + f;
  for (int c = 0; c < 64; ++c) {
    float xv = xp[(size_t)c * (2048 * 64)];
#pragma unroll
    for (int o = 0; o < 16; ++o) qa[o] += Wq[o * 64 + c] * xv;
#pragma unroll
    for (int o = 0; o < 16; ++o) ka[o] += Wk[o * 64 + c] * xv;
#pragma unroll
    for (int o = 0; o < 64; ++o) va[o] += Wv[o * 64 + c] * xv;
  }

#pragma unroll
  for (int h = 0; h < 4; ++h) {
    int hb = h * 2 + b;
    // Q: PReLU + LN(4) + affine; fold attention scale 1/sqrt(256)=1/16 (exact pow2)
    {
      float aa = aq[h];
      float y[4]; float mu = 0.f;
#pragma unroll
      for (int j = 0; j < 4; ++j) { float u = qa[h * 4 + j]; u = u >= 0.f ? u : aa * u; y[j] = u; mu += u; }
      mu *= 0.25f;
      float var = 0.f;
#pragma unroll
      for (int j = 0; j < 4; ++j) { float d = y[j] - mu; var += d * d; }
      float is = rsqrtf(var * 0.25f + 1e-5f);
#pragma unroll
      for (int j = 0; j < 4; ++j) {
        float v = ((y[j] - mu) * is * gq[h * 4 + j] + beq[h * 4 + j]) * 0.0625f;
        store_frag(Qp, hb, t, j * 64 + f, v);
      }
    }
    // K: PReLU + LN(4) + affine
    {
      float aa = ak[h];
      float y[4]; float mu = 0.f;
#pragma unroll
      for (int j = 0; j < 4; ++j) { float u = ka[h * 4 + j]; u = u >= 0.f ? u : aa * u; y[j] = u; mu += u; }
      mu *= 0.25f;
      float var = 0.f;
#pragma unroll
      for (int j = 0; j < 4; ++j) { float d = y[j] - mu; var += d * d; }
      float is = rsqrtf(var * 0.25f + 1e-5f);
#pragma unroll
      for (int j = 0; j < 4; ++j) {
        float v = (y[j] - mu) * is * gk[h * 4 + j] + bek[h * 4 + j];
        store_frag(Kp, hb, t, j * 64 + f, v);
      }
    }
    // V: PReLU + LN(16) + affine, stored directly in PV B-frag layout (hi+lo)
    // B-frag: lane = (dv&15)|(((ts>>3)&3)<<4), elem = ts&7; [hb][t/32][dv/16][lane][8]
    // (identical mapping to R1's validated k_vpack output; dv = vc*64 + f)
    {
      float aa = av[h];
      float y[16]; float mu = 0.f;
#pragma unroll
      for (int j = 0; j < 16; ++j) { float u = va[h * 16 + j]; u = u >= 0.f ? u : aa * u; y[j] = u; mu += u; }
      mu *= 0.0625f;
      float var = 0.f;
#pragma unroll
      for (int j = 0; j < 16; ++j) { float d = y[j] - mu; var += d * d; }
      float is = rsqrtf(var * 0.0625f + 1e-5f);
      int vlane = (f & 15) | (((t >> 3) & 3) << 4);
#pragma unroll
      for (int vc = 0; vc < 16; ++vc) {
        float v = (y[vc] - mu) * is * gv[h * 16 + vc] + bev[h * 16 + vc];
        int dvt = vc * 4 + (f >> 4);
        size_t addr = ((((size_t)hb * 64 + (t >> 5)) * 64 + dvt) << 9) + ((size_t)vlane << 3) + (t & 7);
        ushort_t hh = f2bf(v);
        Vp_hi[addr] = hh;
        Vp_lo[addr] = f2bf(v - bf2f(hh));
      }
    }
  }
}

// ---------------- K2: flash attention ----------------
// grid 512 = [qtile(32) x dvh(2)] x hb(8);  hb = bid&7 -> XCD swizzle.
// wg: 8 waves, 64 q-rows x 512 dv.  QK: wave=(qblk,tsh).  PV: wave=64-dv strip.
// LDS 69.5KB -> 2 wg/CU; VGPR<=128 -> 16 waves/CU (4/SIMD).
// Staging: reg-staged T14 split (issue K(s+1) loads before QK, ds_write after b2).
__global__ __launch_bounds__(512, 4) void k_attn(
    const ushort_t* __restrict__ Qp, const ushort_t* __restrict__ Kp,
    const ushort_t* __restrict__ Vp_hi, const ushort_t* __restrict__ Vp_lo,
    float* __restrict__ O)
{
  extern __shared__ char smem[];
  ushort_t* Kbuf = (ushort_t*)smem;             // [2][16][512]  32KB (dbuf K)
  ushort_t* Qlds = (ushort_t*)(smem + 32768);   // [32][512]     32KB (Q frags)
  ushort_t* Plds = (ushort_t*)(smem + 65536);   // [4][512]      4KB  (P A-frags)
  float* pmax  = (float*)(smem + 69632);        // [2][64]
  float* psum  = (float*)(smem + 70144);        // [2][64]
  float* rsrow = (float*)(smem + 70656);        // [64]
  float* lrow  = (float*)(smem + 70912);        // [64]

  const int lane = threadIdx.x & 63;
  const int wid  = threadIdx.x >> 6;
  const int qblk = wid >> 1;
  const int tsh  = wid & 1;
  const int hb = blockIdx.x & 7;
  const int r2 = blockIdx.x >> 3;
  const int dvh = r2 & 1;
  const int qtile = r2 >> 1;
  const int tb4 = (lane >> 4) << 2;
  const int rowbase = qblk * 16 + tb4;

  // ---- prologue: stage Q (32KB) + K tile 0 (16KB), reg -> LDS ----
  {
    const ushort_t* qsrc = Qp + (((size_t)(hb * 128 + qtile * 4)) << 12) + ((size_t)lane << 3);
#pragma unroll
    for (int i = 0; i < 4; ++i) {
      int c = wid * 4 + i;
      uint4 v = *(const uint4*)(qsrc + ((size_t)c << 9));
      *(uint4*)(Qlds + ((size_t)c << 9) + ((size_t)lane << 3)) = v;
    }
    const ushort_t* ksrc = Kp + (((size_t)(hb * 128)) << 12) + ((size_t)lane << 3);
#pragma unroll
    for (int i = 0; i < 2; ++i) {
      int c = wid * 2 + i;
      uint4 v = *(const uint4*)(ksrc + ((size_t)c << 9));
      *(uint4*)(Kbuf + ((size_t)c << 9) + ((size_t)lane << 3)) = v;
    }
  }
  __syncthreads();

  f32x4 acc[16];
#pragma unroll
  for (int i = 0; i < 16; ++i) acc[i] = (f32x4){0.f, 0.f, 0.f, 0.f};
  float m_run[4], l_run[4];
#pragma unroll
  for (int r = 0; r < 4; ++r) { m_run[r] = -1e30f; l_run[r] = 0.f; }

  for (int s = 0; s < 64; ++s) {
    // ---- T14 issue-early: K(s+1) global -> regs (latency hides under QK+softmax) ----
    uint4 kst0, kst1;
    {
      int sn = (s + 1) & 63;
      const ushort_t* ksrc = Kp + (((size_t)(hb * 128 + 2 * sn)) << 12) + ((size_t)lane << 3);
      kst0 = *(const uint4*)(ksrc + ((size_t)(wid * 2 + 0) << 9));
      kst1 = *(const uint4*)(ksrc + ((size_t)(wid * 2 + 1) << 9));
    }

    const ushort_t* kb = Kbuf + (((size_t)(s & 1)) << 13);
    // ---- QK^T (pure bf16, scale folded into Q) ----
    f32x4 sacc = (f32x4){0.f, 0.f, 0.f, 0.f};
    __builtin_amdgcn_s_setprio(1);
#pragma unroll
    for (int kk = 0; kk < 8; ++kk) {
      bf16x8 qf = *(const bf16x8*)(Qlds + (((size_t)(qblk * 8 + kk)) << 9) + ((size_t)lane << 3));
      bf16x8 kf = *(const bf16x8*)(kb + (((size_t)(tsh * 8 + kk)) << 9) + ((size_t)lane << 3));
      sacc = MFMA16(qf, kf, sacc);
    }
    __builtin_amdgcn_s_setprio(0);
    // partial row-max over our 16 ts
    float rm[4];
#pragma unroll
    for (int r = 0; r < 4; ++r) rm[r] = sacc[r];
#pragma unroll
    for (int m = 1; m <= 8; m <<= 1) {
#pragma unroll
      for (int r = 0; r < 4; ++r) rm[r] = fmaxf(rm[r], __shfl_xor(rm[r], m));
    }
    if ((lane & 15) == 0)
      *(f32x4*)&pmax[tsh * 64 + rowbase] = (f32x4){rm[0], rm[1], rm[2], rm[3]};
    __syncthreads();  // b1: pmax visible

    // ---- P phase ----
    f32x4 pm0 = *(const f32x4*)&pmax[rowbase];
    f32x4 pm1 = *(const f32x4*)&pmax[64 + rowbase];
    float rs[4], pv[4];
#pragma unroll
    for (int r = 0; r < 4; ++r) {
      float mn = fmaxf(m_run[r], fmaxf(pm0[r], pm1[r]));
      rs[r] = __expf(m_run[r] - mn);
      m_run[r] = mn;
      pv[r] = __expf(sacc[r] - mn);
    }
    float ps[4];
#pragma unroll
    for (int r = 0; r < 4; ++r) ps[r] = pv[r];
#pragma unroll
    for (int m = 1; m <= 8; m <<= 1) {
#pragma unroll
      for (int r = 0; r < 4; ++r) ps[r] += __shfl_xor(ps[r], m);
    }
    if ((lane & 15) == 0) {
      *(f32x4*)&psum[tsh * 64 + rowbase] = (f32x4){ps[0], ps[1], ps[2], ps[3]};
      if (tsh == 0)
        *(f32x4*)&rsrow[rowbase] = (f32x4){rs[0], rs[1], rs[2], rs[3]};
    }
    {
      int ts = tsh * 16 + (lane & 15);
      int cs = (ts >> 3) << 4;
      int jj = ts & 7;
#pragma unroll
      for (int r = 0; r < 4; ++r) {
        int tgt = (tb4 + r) | cs;
        Plds[(((size_t)qblk) << 9) + (tgt << 3) + jj] = f2bf(pv[r]);
      }
    }
    __syncthreads();  // b2: P/psum/rsrow visible; K(s+1)'s target buffer fully retired

    // ---- T14 write-late: K(s+1) regs -> LDS (other buffer); hides under PV ----
    {
      ushort_t* kdst = Kbuf + (((size_t)((s + 1) & 1)) << 13) + ((size_t)lane << 3);
      *(uint4*)(kdst + ((size_t)(wid * 2 + 0) << 9)) = kst0;
      *(uint4*)(kdst + ((size_t)(wid * 2 + 1) << 9)) = kst1;
    }

    // ---- PV phase ----
    {
      // l update (tracked redundantly per QK-role rows by both tsh waves)
      {
        f32x4 s0 = *(const f32x4*)&psum[rowbase];
        f32x4 s1 = *(const f32x4*)&psum[64 + rowbase];
#pragma unroll
        for (int r = 0; r < 4; ++r) l_run[r] = l_run[r] * rs[r] + s0[r] + s1[r];
      }
      const int dvt0 = dvh * 32 + wid * 4;
      const ushort_t* vh0 = Vp_hi + ((((size_t)hb * 64 + s) * 64 + dvt0) << 9) + ((size_t)lane << 3);
      const ushort_t* vl0 = Vp_lo + ((((size_t)hb * 64 + s) * 64 + dvt0) << 9) + ((size_t)lane << 3);
#pragma unroll
      for (int ip = 0; ip < 2; ++ip) {
        bf16x8 vh_a = *(const bf16x8*)(vh0 + ((size_t)(ip * 2 + 0) << 9));
        bf16x8 vl_a = *(const bf16x8*)(vl0 + ((size_t)(ip * 2 + 0) << 9));
        bf16x8 vh_b = *(const bf16x8*)(vh0 + ((size_t)(ip * 2 + 1) << 9));
        bf16x8 vl_b = *(const bf16x8*)(vl0 + ((size_t)(ip * 2 + 1) << 9));
        __builtin_amdgcn_s_setprio(1);
#pragma unroll
        for (int q = 0; q < 4; ++q) {
          bf16x8 pf = *(const bf16x8*)(Plds + (((size_t)q) << 9) + ((size_t)lane << 3));
          f32x4 rq = *(const f32x4*)&rsrow[q * 16 + tb4];
          int ia = q * 4 + ip * 2 + 0;
          int ib = q * 4 + ip * 2 + 1;
#pragma unroll
          for (int r = 0; r < 4; ++r) { acc[ia][r] *= rq[r]; acc[ib][r] *= rq[r]; }
          acc[ia] = MFMA16(pf, vh_a, acc[ia]);
          acc[ia] = MFMA16(pf, vl_a, acc[ia]);
          acc[ib] = MFMA16(pf, vh_b, acc[ib]);
          acc[ib] = MFMA16(pf, vl_b, acc[ib]);
        }
        __builtin_amdgcn_s_setprio(0);
      }
    }
    __syncthreads();  // b3: iter end; K(s+1) LDS writes visible for next iter
  }

  // ---- epilogue ----
  if (tsh == 0 && (lane & 15) == 0)
    *(f32x4*)&lrow[rowbase] = (f32x4){l_run[0], l_run[1], l_run[2], l_run[3]};
  __syncthreads();

  const int h = hb >> 1, b = hb & 1;
#pragma unroll
  for (int q = 0; q < 4; ++q) {
    f32x4 lq = *(const f32x4*)&lrow[q * 16 + tb4];
    f32x4 inv;
#pragma unroll
    for (int r = 0; r < 4; ++r) inv[r] = 1.0f / lq[r];
    int trow = qtile * 64 + q * 16 + tb4;
#pragma unroll
    for (int i = 0; i < 4; ++i) {
      int dv = dvh * 512 + wid * 64 + i * 16 + (lane & 15);
      float* op = O + (((size_t)b * 64 + h * 16 + (dv >> 6)) * 2048 + trow) * 64 + (dv & 63);
#pragma unroll
      for (int r = 0; r < 4; ++r) op[(size_t)r * 64] = acc[q * 4 + i][r] * inv[r];
    }
  }
}

// ---------------- K3: output projection + PReLU + LN(64) + residual ----------------
__global__ __launch_bounds__(256) void k_outproj(
    const float* __restrict__ O, const float* __restrict__ Wp, const float* __restrict__ bp,
    const float* __restrict__ ap, const float* __restrict__ gp, const float* __restrict__ bep,
    const float* __restrict__ x, float* __restrict__ out)
{
  int tid = blockIdx.x * 256 + threadIdx.x;
  int f = tid & 63;
  int t = (tid >> 6) & 2047;
  int b = tid >> 17;

  float acc[64];
#pragma unroll
  for (int o = 0; o < 64; ++o) acc[o] = bp[o];
  const float* op_ = O + ((size_t)b * 64 * 2048 + t) * 64 + f;
  for (int c = 0; c < 64; ++c) {
    float ov = op_[(size_t)c * (2048 * 64)];
#pragma unroll
    for (int o = 0; o < 64; ++o) acc[o] += Wp[o * 64 + c] * ov;
  }
  float aa = ap[0];
  float mu = 0.f;
#pragma unroll
  for (int o = 0; o < 64; ++o) { float y = acc[o]; y = y >= 0.f ? y : aa * y; acc[o] = y; mu += y; }
  mu *= 0.015625f;
  float var = 0.f;
#pragma unroll
  for (int o = 0; o < 64; ++o) { float d = acc[o] - mu; var += d * d; }
  float is = rsqrtf(var * 0.015625f + 1e-5f);
  size_t base = ((size_t)b * 64 * 2048 + t) * 64 + f;
#pragma unroll
  for (int o = 0; o < 64; ++o) {
    size_t idx = base + (size_t)o * (2048 * 64);
    out[idx] = (acc[o] - mu) * is * gp[o] + bep[o] + x[idx];
  }
}

extern "C" void kernel_launch(void* const* d_in, const int* in_sizes, int n_in,
                              void* d_out, int out_size, void* d_ws, size_t ws_size,
                              hipStream_t stream) {
  (void)in_sizes; (void)n_in; (void)out_size; (void)ws_size;
  const float* x   = (const float*)d_in[0];
  const float* Wq  = (const float*)d_in[1];
  const float* bq  = (const float*)d_in[2];
  const float* aq  = (const float*)d_in[3];
  const float* gq  = (const float*)d_in[4];
  const float* beq = (const float*)d_in[5];
  const float* Wk  = (const float*)d_in[6];
  const float* bk  = (const float*)d_in[7];
  const float* ak  = (const float*)d_in[8];
  const float* gk  = (const float*)d_in[9];
  const float* bek = (const float*)d_in[10];
  const float* Wv  = (const float*)d_in[11];
  const float* bv  = (const float*)d_in[12];
  const float* av  = (const float*)d_in[13];
  const float* gv  = (const float*)d_in[14];
  const float* bev = (const float*)d_in[15];
  const float* Wp  = (const float*)d_in[16];
  const float* bp  = (const float*)d_in[17];
  const float* ap  = (const float*)d_in[18];
  const float* gp  = (const float*)d_in[19];
  const float* bep = (const float*)d_in[20];

  char* ws = (char*)d_ws;
  const size_t MB = 1024 * 1024;
  ushort_t* Qp    = (ushort_t*)(ws + 0 * MB);    // 8MB  [8][128][8][512]
  ushort_t* Kp    = (ushort_t*)(ws + 8 * MB);    // 8MB
  ushort_t* Vp_hi = (ushort_t*)(ws + 16 * MB);   // 32MB [8][64][64][512]
  ushort_t* Vp_lo = (ushort_t*)(ws + 48 * MB);   // 32MB
  float*    Obuf  = (float*)(ws + 80 * MB);      // 64MB

  hipFuncSetAttribute((const void*)k_attn, hipFuncAttributeMaxDynamicSharedMemorySize, 71168);

  k_proj_qkv<<<1024, 256, 0, stream>>>(x, Wq, bq, aq, gq, beq, Wk, bk, ak, gk, bek,
                                       Wv, bv, av, gv, bev, Qp, Kp, Vp_hi, Vp_lo);
  k_attn<<<512, 512, 71168, stream>>>(Qp, Kp, Vp_hi, Vp_lo, Obuf);
  k_outproj<<<1024, 256, 0, stream>>>(Obuf, Wp, bp, ap, gp, bep, x, (float*)d_out);
}

// Round 5
// 520.165 us; speedup vs baseline: 2.4933x; 1.0681x over previous
//
#include <hip/hip_runtime.h>
#include <stdint.h>

typedef unsigned short ushort_t;
typedef unsigned int u32;
typedef short bf16x8 __attribute__((ext_vector_type(8)));
typedef float f32x4 __attribute__((ext_vector_type(4)));

#define MFMA16(a, b, c) __builtin_amdgcn_mfma_f32_16x16x32_bf16((a), (b), (c), 0, 0, 0)

__device__ __forceinline__ ushort_t f2bf(float f) {
  union { float f; u32 u; } v; v.f = f;
  return (ushort_t)((v.u + 0x7FFFu + ((v.u >> 16) & 1u)) >> 16);
}
__device__ __forceinline__ float bf2f(ushort_t h) {
  union { u32 u; float f; } v; v.u = ((u32)h) << 16;
  return v.f;
}

// ---------------- K1: QKV projection + PReLU + LN(channel), LDS-repacked coalesced stores ----------------
// wg 512 thr = t-tile 16 x f-half 32. grid = 128 tt x 2 fh x 2 b = 512 wgs.
// Frag layouts (validated R1/R4):
//   Q/K: [hb][t/16][d/32][lane][8], lane=(t&15)|(((d>>3)&3)<<4), elem=d&7
//   V:   [hb][t/32][dv/16][lane][8], lane=(dv&15)|(((t>>3)&3)<<4), elem=t&7
__global__ __launch_bounds__(512, 4) void k_proj_qkv(
    const float* __restrict__ x,
    const float* __restrict__ Wq, const float* __restrict__ bq, const float* __restrict__ aq,
    const float* __restrict__ gq, const float* __restrict__ beq,
    const float* __restrict__ Wk, const float* __restrict__ bk, const float* __restrict__ ak,
    const float* __restrict__ gk, const float* __restrict__ bek,
    const float* __restrict__ Wv, const float* __restrict__ bv, const float* __restrict__ av,
    const float* __restrict__ gv, const float* __restrict__ bev,
    ushort_t* __restrict__ Qp, ushort_t* __restrict__ Kp, ushort_t* __restrict__ Vp)
{
  __shared__ ushort_t lds_q[16 * 136];   // row stride 272B: 16B-aligned, uniform-bank b128 reads
  __shared__ ushort_t lds_k[16 * 136];
  __shared__ ushort_t lds_v[512 * 24];   // row stride 48B: 16B-aligned, min-aliasing b128 reads

  const int tid = threadIdx.x;
  const int fi = tid & 31, ti = tid >> 5;        // f-within-half, t-within-tile
  const int lane = tid & 63, wid = tid >> 6;
  const int bid = blockIdx.x;
  const int tt = bid & 127;                      // 16-row t-tile index
  const int fh = (bid >> 7) & 1;
  const int b  = bid >> 8;
  const int t = tt * 16 + ti;
  const int f = fh * 32 + fi;

  // x held in regs: one HBM read total
  float xr[64];
  {
    const float* xp = x + ((size_t)b * 64 * 2048 + t) * 64 + f;
#pragma unroll
    for (int c = 0; c < 64; ++c) xr[c] = xp[(size_t)c * (2048 * 64)];
  }

#pragma unroll 1
  for (int h = 0; h < 4; ++h) {
    const int hb = h * 2 + b;
    float qa[4], ka[4], va[16];
#pragma unroll
    for (int j = 0; j < 4; ++j) { qa[j] = bq[h * 4 + j]; ka[j] = bk[h * 4 + j]; }
#pragma unroll
    for (int j = 0; j < 16; ++j) va[j] = bv[h * 16 + j];
    for (int c = 0; c < 64; ++c) {
      float xv = xr[c];
#pragma unroll
      for (int j = 0; j < 4; ++j) qa[j] += Wq[(h * 4 + j) * 64 + c] * xv;
#pragma unroll
      for (int j = 0; j < 4; ++j) ka[j] += Wk[(h * 4 + j) * 64 + c] * xv;
#pragma unroll
      for (int j = 0; j < 16; ++j) va[j] += Wv[(h * 16 + j) * 64 + c] * xv;
    }
    // Q: PReLU + LN(4) + affine; fold 1/16 attention scale
    {
      float aa = aq[h], mu = 0.f;
#pragma unroll
      for (int j = 0; j < 4; ++j) { float u = qa[j]; u = u >= 0.f ? u : aa * u; qa[j] = u; mu += u; }
      mu *= 0.25f;
      float var = 0.f;
#pragma unroll
      for (int j = 0; j < 4; ++j) { float d = qa[j] - mu; var += d * d; }
      float is = rsqrtf(var * 0.25f + 1e-5f);
#pragma unroll
      for (int j = 0; j < 4; ++j) {
        float v = ((qa[j] - mu) * is * gq[h * 4 + j] + beq[h * 4 + j]) * 0.0625f;
        lds_q[ti * 136 + j * 32 + fi] = f2bf(v);
      }
    }
    // K
    {
      float aa = ak[h], mu = 0.f;
#pragma unroll
      for (int j = 0; j < 4; ++j) { float u = ka[j]; u = u >= 0.f ? u : aa * u; ka[j] = u; mu += u; }
      mu *= 0.25f;
      float var = 0.f;
#pragma unroll
      for (int j = 0; j < 4; ++j) { float d = ka[j] - mu; var += d * d; }
      float is = rsqrtf(var * 0.25f + 1e-5f);
#pragma unroll
      for (int j = 0; j < 4; ++j) {
        float v = (ka[j] - mu) * is * gk[h * 4 + j] + bek[h * 4 + j];
        lds_k[ti * 136 + j * 32 + fi] = f2bf(v);
      }
    }
    // V (bf16 hi only)
    {
      float aa = av[h], mu = 0.f;
#pragma unroll
      for (int j = 0; j < 16; ++j) { float u = va[j]; u = u >= 0.f ? u : aa * u; va[j] = u; mu += u; }
      mu *= 0.0625f;
      float var = 0.f;
#pragma unroll
      for (int j = 0; j < 16; ++j) { float d = va[j] - mu; var += d * d; }
      float is = rsqrtf(var * 0.0625f + 1e-5f);
#pragma unroll
      for (int vc = 0; vc < 16; ++vc) {
        float v = (va[vc] - mu) * is * gv[h * 16 + vc] + bev[h * 16 + vc];
        lds_v[(vc * 32 + fi) * 24 + ti] = f2bf(v);
      }
    }
    __syncthreads();

    // ---- coalesced frag stores ----
    // Q/K: wave wid<4 -> Q frag j=wid; wid>=4 -> K frag j=wid-4. 1KB per wave.
    {
      int j = wid & 3;
      const ushort_t* src = (wid < 4) ? lds_q : lds_k;
      uint4 v = *(const uint4*)&src[(lane & 15) * 136 + j * 32 + ((lane >> 4) << 3)];
      size_t base = ((((size_t)hb * 128 + tt) * 8) + (2 * j + fh)) << 9;
      ushort_t* dst = (wid < 4) ? Qp : Kp;
      *(uint4*)(dst + base + ((size_t)lane << 3)) = v;
    }
    // V: 32 half-frags (this wg covers t%32 half = tt&1), 4 per wave, 512B predicated stores
    {
      const int halfsel = tt & 1;
      const bool act = (lane >> 5) == halfsel;
#pragma unroll
      for (int i = 0; i < 4; ++i) {
        int gl = wid * 4 + i;
        int vc = gl >> 1, u = gl & 1;
        int row = vc * 32 + u * 16 + (lane & 15);
        uint4 v = *(const uint4*)&lds_v[row * 24 + (((lane >> 4) & 1) << 3)];
        int g = vc * 4 + fh * 2 + u;
        size_t base = (((size_t)hb * 64 + (tt >> 1)) * 64 + g) << 9;
        if (act) *(uint4*)(Vp + base + ((size_t)lane << 3)) = v;
      }
    }
    __syncthreads();  // LDS reusable for next h
  }
}

// ---------------- K2: flash attention ----------------
// grid 512 = [qtile(32) x dvh(2)] x hb(8); hb = bid&7 -> XCD swizzle.
// PV pure bf16 (V-lo dropped). T13 defer-rescale per qblk. T14 reg-staged K prefetch.
__global__ __launch_bounds__(512, 4) void k_attn(
    const ushort_t* __restrict__ Qp, const ushort_t* __restrict__ Kp,
    const ushort_t* __restrict__ Vp, ushort_t* __restrict__ O)
{
  extern __shared__ char smem[];
  ushort_t* Kbuf = (ushort_t*)smem;             // [2][16][512]  32KB (dbuf K)
  ushort_t* Qlds = (ushort_t*)(smem + 32768);   // [32][512]     32KB (Q frags)
  ushort_t* Plds = (ushort_t*)(smem + 65536);   // [4][512]      4KB  (P A-frags)
  float* pmax  = (float*)(smem + 69632);        // [2][64]
  float* psum  = (float*)(smem + 70144);        // [2][64]
  float* rsrow = (float*)(smem + 70656);        // [64]
  float* lrow  = (float*)(smem + 70912);        // [64]
  int*   skipf = (int*)(smem + 71168);          // [4]

  const int lane = threadIdx.x & 63;
  const int wid  = threadIdx.x >> 6;
  const int qblk = wid >> 1;
  const int tsh  = wid & 1;
  const int hb = blockIdx.x & 7;
  const int r2 = blockIdx.x >> 3;
  const int dvh = r2 & 1;
  const int qtile = r2 >> 1;
  const int tb4 = (lane >> 4) << 2;
  const int rowbase = qblk * 16 + tb4;

  // prologue: Q (32KB) + K tile 0 (16KB) reg->LDS
  {
    const ushort_t* qsrc = Qp + (((size_t)(hb * 128 + qtile * 4)) << 12) + ((size_t)lane << 3);
#pragma unroll
    for (int i = 0; i < 4; ++i) {
      int c = wid * 4 + i;
      *(uint4*)(Qlds + ((size_t)c << 9) + ((size_t)lane << 3)) = *(const uint4*)(qsrc + ((size_t)c << 9));
    }
    const ushort_t* ksrc = Kp + (((size_t)(hb * 128)) << 12) + ((size_t)lane << 3);
#pragma unroll
    for (int i = 0; i < 2; ++i) {
      int c = wid * 2 + i;
      *(uint4*)(Kbuf + ((size_t)c << 9) + ((size_t)lane << 3)) = *(const uint4*)(ksrc + ((size_t)c << 9));
    }
  }
  __syncthreads();

  f32x4 acc[16];
#pragma unroll
  for (int i = 0; i < 16; ++i) acc[i] = (f32x4){0.f, 0.f, 0.f, 0.f};
  float m_run[4], l_run[4];
#pragma unroll
  for (int r = 0; r < 4; ++r) { m_run[r] = -1e30f; l_run[r] = 0.f; }

  for (int s = 0; s < 64; ++s) {
    // T14 issue-early: K(s+1) global -> regs
    uint4 kst0, kst1;
    {
      int sn = (s + 1) & 63;
      const ushort_t* ksrc = Kp + (((size_t)(hb * 128 + 2 * sn)) << 12) + ((size_t)lane << 3);
      kst0 = *(const uint4*)(ksrc + ((size_t)(wid * 2 + 0) << 9));
      kst1 = *(const uint4*)(ksrc + ((size_t)(wid * 2 + 1) << 9));
    }

    const ushort_t* kb = Kbuf + (((size_t)(s & 1)) << 13);
    // QK^T (bf16, scale folded into Q)
    f32x4 sacc = (f32x4){0.f, 0.f, 0.f, 0.f};
    __builtin_amdgcn_s_setprio(1);
#pragma unroll
    for (int kk = 0; kk < 8; ++kk) {
      bf16x8 qf = *(const bf16x8*)(Qlds + (((size_t)(qblk * 8 + kk)) << 9) + ((size_t)lane << 3));
      bf16x8 kf = *(const bf16x8*)(kb + (((size_t)(tsh * 8 + kk)) << 9) + ((size_t)lane << 3));
      sacc = MFMA16(qf, kf, sacc);
    }
    __builtin_amdgcn_s_setprio(0);
    // partial row-max
    float rm[4];
#pragma unroll
    for (int r = 0; r < 4; ++r) rm[r] = sacc[r];
#pragma unroll
    for (int m = 1; m <= 8; m <<= 1) {
#pragma unroll
      for (int r = 0; r < 4; ++r) rm[r] = fmaxf(rm[r], __shfl_xor(rm[r], m));
    }
    if ((lane & 15) == 0)
      *(f32x4*)&pmax[tsh * 64 + rowbase] = (f32x4){rm[0], rm[1], rm[2], rm[3]};
    __syncthreads();  // b1: pmax visible

    // P phase with T13 defer-rescale
    f32x4 pm0 = *(const f32x4*)&pmax[rowbase];
    f32x4 pm1 = *(const f32x4*)&pmax[64 + rowbase];
    float mn[4], rs[4], pv[4];
    int okl = 1;
#pragma unroll
    for (int r = 0; r < 4; ++r) {
      mn[r] = fmaxf(m_run[r], fmaxf(pm0[r], pm1[r]));
      okl &= (mn[r] - m_run[r] <= 8.0f) ? 1 : 0;
    }
    const int ok = __all(okl);
    if (!ok) {
#pragma unroll
      for (int r = 0; r < 4; ++r) { rs[r] = __expf(m_run[r] - mn[r]); m_run[r] = mn[r]; }
    } else {
#pragma unroll
      for (int r = 0; r < 4; ++r) rs[r] = 1.0f;
    }
#pragma unroll
    for (int r = 0; r < 4; ++r) pv[r] = __expf(sacc[r] - m_run[r]);
    float ps[4];
#pragma unroll
    for (int r = 0; r < 4; ++r) ps[r] = pv[r];
#pragma unroll
    for (int m = 1; m <= 8; m <<= 1) {
#pragma unroll
      for (int r = 0; r < 4; ++r) ps[r] += __shfl_xor(ps[r], m);
    }
    if ((lane & 15) == 0) {
      *(f32x4*)&psum[tsh * 64 + rowbase] = (f32x4){ps[0], ps[1], ps[2], ps[3]};
      if (tsh == 0)
        *(f32x4*)&rsrow[rowbase] = (f32x4){rs[0], rs[1], rs[2], rs[3]};
    }
    if (tsh == 0 && lane == 0) skipf[qblk] = ok;
    {
      int ts = tsh * 16 + (lane & 15);
      int cs = (ts >> 3) << 4;
      int jj = ts & 7;
#pragma unroll
      for (int r = 0; r < 4; ++r) {
        int tgt = (tb4 + r) | cs;
        Plds[(((size_t)qblk) << 9) + (tgt << 3) + jj] = f2bf(pv[r]);
      }
    }
    __syncthreads();  // b2: P/psum/rsrow/skipf visible; K(s+1) target buffer retired

    // T14 write-late: K(s+1) regs -> LDS (hides under PV)
    {
      ushort_t* kdst = Kbuf + (((size_t)((s + 1) & 1)) << 13) + ((size_t)lane << 3);
      *(uint4*)(kdst + ((size_t)(wid * 2 + 0) << 9)) = kst0;
      *(uint4*)(kdst + ((size_t)(wid * 2 + 1) << 9)) = kst1;
    }

    // PV phase (pure bf16)
    {
      {
        f32x4 s0 = *(const f32x4*)&psum[rowbase];
        f32x4 s1 = *(const f32x4*)&psum[64 + rowbase];
#pragma unroll
        for (int r = 0; r < 4; ++r) l_run[r] = l_run[r] * rs[r] + s0[r] + s1[r];
      }
      const int dvt0 = dvh * 32 + wid * 4;
      const ushort_t* vh0 = Vp + ((((size_t)hb * 64 + s) * 64 + dvt0) << 9) + ((size_t)lane << 3);
#pragma unroll
      for (int ip = 0; ip < 2; ++ip) {
        bf16x8 vh_a = *(const bf16x8*)(vh0 + ((size_t)(ip * 2 + 0) << 9));
        bf16x8 vh_b = *(const bf16x8*)(vh0 + ((size_t)(ip * 2 + 1) << 9));
        __builtin_amdgcn_s_setprio(1);
#pragma unroll
        for (int q = 0; q < 4; ++q) {
          bf16x8 pf = *(const bf16x8*)(Plds + (((size_t)q) << 9) + ((size_t)lane << 3));
          int ia = q * 4 + ip * 2 + 0;
          int ib = q * 4 + ip * 2 + 1;
          if (!skipf[q]) {
            f32x4 rq = *(const f32x4*)&rsrow[q * 16 + tb4];
#pragma unroll
            for (int r = 0; r < 4; ++r) { acc[ia][r] *= rq[r]; acc[ib][r] *= rq[r]; }
          }
          acc[ia] = MFMA16(pf, vh_a, acc[ia]);
          acc[ib] = MFMA16(pf, vh_b, acc[ib]);
        }
        __builtin_amdgcn_s_setprio(0);
      }
    }
    __syncthreads();  // b3: iter end
  }

  // epilogue: normalize, store Obuf as bf16 [B][C][T][F]
  if (tsh == 0 && (lane & 15) == 0)
    *(f32x4*)&lrow[rowbase] = (f32x4){l_run[0], l_run[1], l_run[2], l_run[3]};
  __syncthreads();

  const int h = hb >> 1, b = hb & 1;
#pragma unroll
  for (int q = 0; q < 4; ++q) {
    f32x4 lq = *(const f32x4*)&lrow[q * 16 + tb4];
    f32x4 inv;
#pragma unroll
    for (int r = 0; r < 4; ++r) inv[r] = 1.0f / lq[r];
    int trow = qtile * 64 + q * 16 + tb4;
#pragma unroll
    for (int i = 0; i < 4; ++i) {
      int dv = dvh * 512 + wid * 64 + i * 16 + (lane & 15);
      ushort_t* op = O + (((size_t)b * 64 + h * 16 + (dv >> 6)) * 2048 + trow) * 64 + (dv & 63);
#pragma unroll
      for (int r = 0; r < 4; ++r) op[(size_t)r * 64] = f2bf(acc[q * 4 + i][r] * inv[r]);
    }
  }
}

// ---------------- K3: output projection + PReLU + LN(64) + residual ----------------
__global__ __launch_bounds__(256) void k_outproj(
    const ushort_t* __restrict__ O, const float* __restrict__ Wp, const float* __restrict__ bp,
    const float* __restrict__ ap, const float* __restrict__ gp, const float* __restrict__ bep,
    const float* __restrict__ x, float* __restrict__ out)
{
  int tid = blockIdx.x * 256 + threadIdx.x;
  int f = tid & 63;
  int t = (tid >> 6) & 2047;
  int b = tid >> 17;

  float acc[64];
#pragma unroll
  for (int o = 0; o < 64; ++o) acc[o] = bp[o];
  const ushort_t* op_ = O + ((size_t)b * 64 * 2048 + t) * 64 + f;
  for (int c = 0; c < 64; ++c) {
    float ov = bf2f(op_[(size_t)c * (2048 * 64)]);
#pragma unroll
    for (int o = 0; o < 64; ++o) acc[o] += Wp[o * 64 + c] * ov;
  }
  float aa = ap[0];
  float mu = 0.f;
#pragma unroll
  for (int o = 0; o < 64; ++o) { float y = acc[o]; y = y >= 0.f ? y : aa * y; acc[o] = y; mu += y; }
  mu *= 0.015625f;
  float var = 0.f;
#pragma unroll
  for (int o = 0; o < 64; ++o) { float d = acc[o] - mu; var += d * d; }
  float is = rsqrtf(var * 0.015625f + 1e-5f);
  size_t base = ((size_t)b * 64 * 2048 + t) * 64 + f;
#pragma unroll
  for (int o = 0; o < 64; ++o) {
    size_t idx = base + (size_t)o * (2048 * 64);
    out[idx] = (acc[o] - mu) * is * gp[o] + bep[o] + x[idx];
  }
}

extern "C" void kernel_launch(void* const* d_in, const int* in_sizes, int n_in,
                              void* d_out, int out_size, void* d_ws, size_t ws_size,
                              hipStream_t stream) {
  (void)in_sizes; (void)n_in; (void)out_size; (void)ws_size;
  const float* x   = (const float*)d_in[0];
  const float* Wq  = (const float*)d_in[1];
  const float* bq  = (const float*)d_in[2];
  const float* aq  = (const float*)d_in[3];
  const float* gq  = (const float*)d_in[4];
  const float* beq = (const float*)d_in[5];
  const float* Wk  = (const float*)d_in[6];
  const float* bk  = (const float*)d_in[7];
  const float* ak  = (const float*)d_in[8];
  const float* gk  = (const float*)d_in[9];
  const float* bek = (const float*)d_in[10];
  const float* Wv  = (const float*)d_in[11];
  const float* bv  = (const float*)d_in[12];
  const float* av  = (const float*)d_in[13];
  const float* gv  = (const float*)d_in[14];
  const float* bev = (const float*)d_in[15];
  const float* Wp  = (const float*)d_in[16];
  const float* bp  = (const float*)d_in[17];
  const float* ap  = (const float*)d_in[18];
  const float* gp  = (const float*)d_in[19];
  const float* bep = (const float*)d_in[20];

  char* ws = (char*)d_ws;
  const size_t MB = 1024 * 1024;
  ushort_t* Qp   = (ushort_t*)(ws + 0 * MB);    // 8MB  [8][128][8][512]
  ushort_t* Kp   = (ushort_t*)(ws + 8 * MB);    // 8MB
  ushort_t* Vp   = (ushort_t*)(ws + 16 * MB);   // 32MB [8][64][64][512]
  ushort_t* Obuf = (ushort_t*)(ws + 48 * MB);   // 32MB bf16 [2][64][2048][64]

  hipFuncSetAttribute((const void*)k_attn, hipFuncAttributeMaxDynamicSharedMemorySize, 71296);

  k_proj_qkv<<<512, 512, 0, stream>>>(x, Wq, bq, aq, gq, beq, Wk, bk, ak, gk, bek,
                                      Wv, bv, av, gv, bev, Qp, Kp, Vp);
  k_attn<<<512, 512, 71296, stream>>>(Qp, Kp, Vp, Obuf);
  k_outproj<<<1024, 256, 0, stream>>>(Obuf, Wp, bp, ap, gp, bep, x, (float*)d_out);
}

// Round 7
// 519.217 us; speedup vs baseline: 2.4979x; 1.0018x over previous
//
#include <hip/hip_runtime.h>
#include <stdint.h>

typedef unsigned short ushort_t;
typedef unsigned int u32;
typedef short bf16x8 __attribute__((ext_vector_type(8)));
typedef float f32x4 __attribute__((ext_vector_type(4)));

#define MFMA16(a, b, c) __builtin_amdgcn_mfma_f32_16x16x32_bf16((a), (b), (c), 0, 0, 0)

__device__ __forceinline__ ushort_t f2bf(float f) {
  union { float f; u32 u; } v; v.f = f;
  return (ushort_t)((v.u + 0x7FFFu + ((v.u >> 16) & 1u)) >> 16);
}
__device__ __forceinline__ float bf2f(ushort_t h) {
  union { u32 u; float f; } v; v.u = ((u32)h) << 16;
  return v.f;
}

// ---------------- K1: QKV projection + PReLU + LN(channel), LDS-repacked coalesced stores ----------------
// wg 512 thr = t-tile 16 x f-half 32. grid = 128 tt x 2 fh x 2 b = 512 wgs.
// Frag layouts (validated R1/R4/R5):
//   Q/K: [hb][t/16][d/32][lane][8], lane=(t&15)|(((d>>3)&3)<<4), elem=d&7
//   V:   [hb][t/32][dv/16][lane][8], lane=(dv&15)|(((t>>3)&3)<<4), elem=t&7
__global__ __launch_bounds__(512, 2) void k_proj_qkv(
    const float* __restrict__ x,
    const float* __restrict__ Wq, const float* __restrict__ bq, const float* __restrict__ aq,
    const float* __restrict__ gq, const float* __restrict__ beq,
    const float* __restrict__ Wk, const float* __restrict__ bk, const float* __restrict__ ak,
    const float* __restrict__ gk, const float* __restrict__ bek,
    const float* __restrict__ Wv, const float* __restrict__ bv, const float* __restrict__ av,
    const float* __restrict__ gv, const float* __restrict__ bev,
    ushort_t* __restrict__ Qp, ushort_t* __restrict__ Kp, ushort_t* __restrict__ Vp)
{
  __shared__ ushort_t lds_q[16 * 136];
  __shared__ ushort_t lds_k[16 * 136];
  __shared__ ushort_t lds_v[512 * 24];

  const int tid = threadIdx.x;
  const int fi = tid & 31, ti = tid >> 5;
  const int lane = tid & 63, wid = tid >> 6;
  const int bid = blockIdx.x;
  const int tt = bid & 127;
  const int fh = (bid >> 7) & 1;
  const int b  = bid >> 8;
  const int t = tt * 16 + ti;
  const int f = fh * 32 + fi;

  float xr[64];
  {
    const float* xp = x + ((size_t)b * 64 * 2048 + t) * 64 + f;
#pragma unroll
    for (int c = 0; c < 64; ++c) xr[c] = xp[(size_t)c * (2048 * 64)];
  }

#pragma unroll 1
  for (int h = 0; h < 4; ++h) {
    const int hb = h * 2 + b;
    float qa[4], ka[4], va[16];
#pragma unroll
    for (int j = 0; j < 4; ++j) { qa[j] = bq[h * 4 + j]; ka[j] = bk[h * 4 + j]; }
#pragma unroll
    for (int j = 0; j < 16; ++j) va[j] = bv[h * 16 + j];
    for (int c = 0; c < 64; ++c) {
      float xv = xr[c];
#pragma unroll
      for (int j = 0; j < 4; ++j) qa[j] += Wq[(h * 4 + j) * 64 + c] * xv;
#pragma unroll
      for (int j = 0; j < 4; ++j) ka[j] += Wk[(h * 4 + j) * 64 + c] * xv;
#pragma unroll
      for (int j = 0; j < 16; ++j) va[j] += Wv[(h * 16 + j) * 64 + c] * xv;
    }
    {
      float aa = aq[h], mu = 0.f;
#pragma unroll
      for (int j = 0; j < 4; ++j) { float u = qa[j]; u = u >= 0.f ? u : aa * u; qa[j] = u; mu += u; }
      mu *= 0.25f;
      float var = 0.f;
#pragma unroll
      for (int j = 0; j < 4; ++j) { float d = qa[j] - mu; var += d * d; }
      float is = rsqrtf(var * 0.25f + 1e-5f);
#pragma unroll
      for (int j = 0; j < 4; ++j) {
        float v = ((qa[j] - mu) * is * gq[h * 4 + j] + beq[h * 4 + j]) * 0.0625f;
        lds_q[ti * 136 + j * 32 + fi] = f2bf(v);
      }
    }
    {
      float aa = ak[h], mu = 0.f;
#pragma unroll
      for (int j = 0; j < 4; ++j) { float u = ka[j]; u = u >= 0.f ? u : aa * u; ka[j] = u; mu += u; }
      mu *= 0.25f;
      float var = 0.f;
#pragma unroll
      for (int j = 0; j < 4; ++j) { float d = ka[j] - mu; var += d * d; }
      float is = rsqrtf(var * 0.25f + 1e-5f);
#pragma unroll
      for (int j = 0; j < 4; ++j) {
        float v = (ka[j] - mu) * is * gk[h * 4 + j] + bek[h * 4 + j];
        lds_k[ti * 136 + j * 32 + fi] = f2bf(v);
      }
    }
    {
      float aa = av[h], mu = 0.f;
#pragma unroll
      for (int j = 0; j < 16; ++j) { float u = va[j]; u = u >= 0.f ? u : aa * u; va[j] = u; mu += u; }
      mu *= 0.0625f;
      float var = 0.f;
#pragma unroll
      for (int j = 0; j < 16; ++j) { float d = va[j] - mu; var += d * d; }
      float is = rsqrtf(var * 0.0625f + 1e-5f);
#pragma unroll
      for (int vc = 0; vc < 16; ++vc) {
        float v = (va[vc] - mu) * is * gv[h * 16 + vc] + bev[h * 16 + vc];
        lds_v[(vc * 32 + fi) * 24 + ti] = f2bf(v);
      }
    }
    __syncthreads();

    {
      int j = wid & 3;
      const ushort_t* src = (wid < 4) ? lds_q : lds_k;
      uint4 v = *(const uint4*)&src[(lane & 15) * 136 + j * 32 + ((lane >> 4) << 3)];
      size_t base = ((((size_t)hb * 128 + tt) * 8) + (2 * j + fh)) << 9;
      ushort_t* dst = (wid < 4) ? Qp : Kp;
      *(uint4*)(dst + base + ((size_t)lane << 3)) = v;
    }
    {
      const int halfsel = tt & 1;
      const bool act = (lane >> 5) == halfsel;
#pragma unroll
      for (int i = 0; i < 4; ++i) {
        int gl = wid * 4 + i;
        int vc = gl >> 1, u = gl & 1;
        int row = vc * 32 + u * 16 + (lane & 15);
        uint4 v = *(const uint4*)&lds_v[row * 24 + (((lane >> 4) & 1) << 3)];
        int g = vc * 4 + fh * 2 + u;
        size_t base = (((size_t)hb * 64 + (tt >> 1)) * 64 + g) << 9;
        if (act) *(uint4*)(Vp + base + ((size_t)lane << 3)) = v;
      }
    }
    __syncthreads();
  }
}

// ---------------- K2: flash attention ----------------
// grid 512 = [qtile(32) x dvh(2)] x hb(8); hb = bid&7 -> XCD swizzle.
// Epilogue writes Obuf in the OUTPROJ B-frag layout: [pfi][kf][lane][8],
// lane=(pos&15)|(((c>>3)&3)<<4), elem=c&7, pfi=(b*8192 + pos>>4), pos=t*64+f.
__global__ __launch_bounds__(512, 4) void k_attn(
    const ushort_t* __restrict__ Qp, const ushort_t* __restrict__ Kp,
    const ushort_t* __restrict__ Vp, ushort_t* __restrict__ Ofrag)
{
  extern __shared__ char smem[];
  ushort_t* Kbuf = (ushort_t*)smem;             // [2][16][512]  32KB (dbuf K)
  ushort_t* Qlds = (ushort_t*)(smem + 32768);   // [32][512]     32KB (Q frags)
  ushort_t* Plds = (ushort_t*)(smem + 65536);   // [4][512]      4KB
  float* pmax  = (float*)(smem + 69632);
  float* psum  = (float*)(smem + 70144);
  float* rsrow = (float*)(smem + 70656);
  float* lrow  = (float*)(smem + 70912);
  int*   skipf = (int*)(smem + 71168);
  ushort_t* Olds = (ushort_t*)smem;             // 64KB [64 tl][64 f][8 c''] (epilogue reuse)

  const int lane = threadIdx.x & 63;
  const int wid  = threadIdx.x >> 6;
  const int qblk = wid >> 1;
  const int tsh  = wid & 1;
  const int hb = blockIdx.x & 7;
  const int r2 = blockIdx.x >> 3;
  const int dvh = r2 & 1;
  const int qtile = r2 >> 1;
  const int tb4 = (lane >> 4) << 2;
  const int rowbase = qblk * 16 + tb4;

  {
    const ushort_t* qsrc = Qp + (((size_t)(hb * 128 + qtile * 4)) << 12) + ((size_t)lane << 3);
#pragma unroll
    for (int i = 0; i < 4; ++i) {
      int c = wid * 4 + i;
      *(uint4*)(Qlds + ((size_t)c << 9) + ((size_t)lane << 3)) = *(const uint4*)(qsrc + ((size_t)c << 9));
    }
    const ushort_t* ksrc = Kp + (((size_t)(hb * 128)) << 12) + ((size_t)lane << 3);
#pragma unroll
    for (int i = 0; i < 2; ++i) {
      int c = wid * 2 + i;
      *(uint4*)(Kbuf + ((size_t)c << 9) + ((size_t)lane << 3)) = *(const uint4*)(ksrc + ((size_t)c << 9));
    }
  }
  __syncthreads();

  f32x4 acc[16];
#pragma unroll
  for (int i = 0; i < 16; ++i) acc[i] = (f32x4){0.f, 0.f, 0.f, 0.f};
  float m_run[4], l_run[4];
#pragma unroll
  for (int r = 0; r < 4; ++r) { m_run[r] = -1e30f; l_run[r] = 0.f; }

  for (int s = 0; s < 64; ++s) {
    uint4 kst0, kst1;
    {
      int sn = (s + 1) & 63;
      const ushort_t* ksrc = Kp + (((size_t)(hb * 128 + 2 * sn)) << 12) + ((size_t)lane << 3);
      kst0 = *(const uint4*)(ksrc + ((size_t)(wid * 2 + 0) << 9));
      kst1 = *(const uint4*)(ksrc + ((size_t)(wid * 2 + 1) << 9));
    }

    const ushort_t* kb = Kbuf + (((size_t)(s & 1)) << 13);
    f32x4 sacc = (f32x4){0.f, 0.f, 0.f, 0.f};
    __builtin_amdgcn_s_setprio(1);
#pragma unroll
    for (int kk = 0; kk < 8; ++kk) {
      bf16x8 qf = *(const bf16x8*)(Qlds + (((size_t)(qblk * 8 + kk)) << 9) + ((size_t)lane << 3));
      bf16x8 kf = *(const bf16x8*)(kb + (((size_t)(tsh * 8 + kk)) << 9) + ((size_t)lane << 3));
      sacc = MFMA16(qf, kf, sacc);
    }
    __builtin_amdgcn_s_setprio(0);
    float rm[4];
#pragma unroll
    for (int r = 0; r < 4; ++r) rm[r] = sacc[r];
#pragma unroll
    for (int m = 1; m <= 8; m <<= 1) {
#pragma unroll
      for (int r = 0; r < 4; ++r) rm[r] = fmaxf(rm[r], __shfl_xor(rm[r], m));
    }
    if ((lane & 15) == 0)
      *(f32x4*)&pmax[tsh * 64 + rowbase] = (f32x4){rm[0], rm[1], rm[2], rm[3]};
    __syncthreads();  // b1

    f32x4 pm0 = *(const f32x4*)&pmax[rowbase];
    f32x4 pm1 = *(const f32x4*)&pmax[64 + rowbase];
    float mn[4], rs[4], pv[4];
    int okl = 1;
#pragma unroll
    for (int r = 0; r < 4; ++r) {
      mn[r] = fmaxf(m_run[r], fmaxf(pm0[r], pm1[r]));
      okl &= (mn[r] - m_run[r] <= 8.0f) ? 1 : 0;
    }
    const int ok = __all(okl);
    if (!ok) {
#pragma unroll
      for (int r = 0; r < 4; ++r) { rs[r] = __expf(m_run[r] - mn[r]); m_run[r] = mn[r]; }
    } else {
#pragma unroll
      for (int r = 0; r < 4; ++r) rs[r] = 1.0f;
    }
#pragma unroll
    for (int r = 0; r < 4; ++r) pv[r] = __expf(sacc[r] - m_run[r]);
    float ps[4];
#pragma unroll
    for (int r = 0; r < 4; ++r) ps[r] = pv[r];
#pragma unroll
    for (int m = 1; m <= 8; m <<= 1) {
#pragma unroll
      for (int r = 0; r < 4; ++r) ps[r] += __shfl_xor(ps[r], m);
    }
    if ((lane & 15) == 0) {
      *(f32x4*)&psum[tsh * 64 + rowbase] = (f32x4){ps[0], ps[1], ps[2], ps[3]};
      if (tsh == 0)
        *(f32x4*)&rsrow[rowbase] = (f32x4){rs[0], rs[1], rs[2], rs[3]};
    }
    if (tsh == 0 && lane == 0) skipf[qblk] = ok;
    {
      int ts = tsh * 16 + (lane & 15);
      int cs = (ts >> 3) << 4;
      int jj = ts & 7;
#pragma unroll
      for (int r = 0; r < 4; ++r) {
        int tgt = (tb4 + r) | cs;
        Plds[(((size_t)qblk) << 9) + (tgt << 3) + jj] = f2bf(pv[r]);
      }
    }
    __syncthreads();  // b2

    {
      ushort_t* kdst = Kbuf + (((size_t)((s + 1) & 1)) << 13) + ((size_t)lane << 3);
      *(uint4*)(kdst + ((size_t)(wid * 2 + 0) << 9)) = kst0;
      *(uint4*)(kdst + ((size_t)(wid * 2 + 1) << 9)) = kst1;
    }

    {
      {
        f32x4 s0 = *(const f32x4*)&psum[rowbase];
        f32x4 s1 = *(const f32x4*)&psum[64 + rowbase];
#pragma unroll
        for (int r = 0; r < 4; ++r) l_run[r] = l_run[r] * rs[r] + s0[r] + s1[r];
      }
      const int dvt0 = dvh * 32 + wid * 4;
      const ushort_t* vh0 = Vp + ((((size_t)hb * 64 + s) * 64 + dvt0) << 9) + ((size_t)lane << 3);
#pragma unroll
      for (int ip = 0; ip < 2; ++ip) {
        bf16x8 vh_a = *(const bf16x8*)(vh0 + ((size_t)(ip * 2 + 0) << 9));
        bf16x8 vh_b = *(const bf16x8*)(vh0 + ((size_t)(ip * 2 + 1) << 9));
        __builtin_amdgcn_s_setprio(1);
#pragma unroll
        for (int q = 0; q < 4; ++q) {
          bf16x8 pf = *(const bf16x8*)(Plds + (((size_t)q) << 9) + ((size_t)lane << 3));
          int ia = q * 4 + ip * 2 + 0;
          int ib = q * 4 + ip * 2 + 1;
          if (!skipf[q]) {
            f32x4 rq = *(const f32x4*)&rsrow[q * 16 + tb4];
#pragma unroll
            for (int r = 0; r < 4; ++r) { acc[ia][r] *= rq[r]; acc[ib][r] *= rq[r]; }
          }
          acc[ia] = MFMA16(pf, vh_a, acc[ia]);
          acc[ib] = MFMA16(pf, vh_b, acc[ib]);
        }
        __builtin_amdgcn_s_setprio(0);
      }
    }
    __syncthreads();  // b3
  }

  // ---- epilogue: normalize -> LDS repack -> coalesced frag stores ----
  if (tsh == 0 && (lane & 15) == 0)
    *(f32x4*)&lrow[rowbase] = (f32x4){l_run[0], l_run[1], l_run[2], l_run[3]};
  __syncthreads();

  const int h = hb >> 1, b = hb & 1;
  // per lane: c'' = wid, f = i*16+(lane&15), tl = q*16+tb4+r
#pragma unroll
  for (int q = 0; q < 4; ++q) {
    f32x4 lq = *(const f32x4*)&lrow[q * 16 + tb4];
    f32x4 inv;
#pragma unroll
    for (int r = 0; r < 4; ++r) inv[r] = 1.0f / lq[r];
#pragma unroll
    for (int i = 0; i < 4; ++i) {
      int fcol = i * 16 + (lane & 15);
#pragma unroll
      for (int r = 0; r < 4; ++r) {
        int tl = q * 16 + tb4 + r;
        Olds[((size_t)(tl * 64 + fcol) << 3) + wid] = f2bf(acc[q * 4 + i][r] * inv[r]);
      }
    }
  }
  __syncthreads();

  const int kf = (h * 2 + dvh) >> 2;
  const int lgrp = (h * 2 + dvh) & 3;
  const size_t pfibase = (size_t)(b * 8192 + qtile * 256);
#pragma unroll
  for (int grp = 0; grp < 8; ++grp) {
    int tl = wid * 8 + grp;
    int fq = lane >> 4, l = lane & 15;
    uint4 v = *(const uint4*)&Olds[(size_t)(tl * 64 + fq * 16 + l) << 3];
    size_t pfi = pfibase + tl * 4 + fq;
    *(uint4*)(Ofrag + ((pfi * 2 + kf) << 9) + ((size_t)(lgrp * 16 + l) << 3)) = v;
  }
}

// ---------------- K3: output projection as MFMA GEMM + PReLU + LN(64) + residual ----------------
// grid 1024 x 256 thr. Wave handles 4 pos-tiles of 16 pos. W bf16 A-frags in regs.
__global__ __launch_bounds__(256) void k_outproj(
    const ushort_t* __restrict__ Ofrag, const float* __restrict__ Wp, const float* __restrict__ bp,
    const float* __restrict__ ap, const float* __restrict__ gp, const float* __restrict__ bep,
    const float* __restrict__ x, float* __restrict__ out)
{
  const int lane = threadIdx.x & 63;
  const int wid  = threadIdx.x >> 6;

  // A-frags: a[mt][kfr]: lane holds m=mt*16+(lane&15), c = kfr*32+(lane>>4)*8+e
  bf16x8 a[4][2];
#pragma unroll
  for (int mt = 0; mt < 4; ++mt) {
#pragma unroll
    for (int kfr = 0; kfr < 2; ++kfr) {
      const float* wsrc = Wp + (size_t)(mt * 16 + (lane & 15)) * 64 + kfr * 32 + ((lane >> 4) << 3);
      float4 w0 = *(const float4*)wsrc;
      float4 w1 = *(const float4*)(wsrc + 4);
      bf16x8 af;
      af[0] = (short)f2bf(w0.x); af[1] = (short)f2bf(w0.y);
      af[2] = (short)f2bf(w0.z); af[3] = (short)f2bf(w0.w);
      af[4] = (short)f2bf(w1.x); af[5] = (short)f2bf(w1.y);
      af[6] = (short)f2bf(w1.z); af[7] = (short)f2bf(w1.w);
      a[mt][kfr] = af;
    }
  }
  // per-lane bias/gain/beta: o = mt*16 + (lane>>4)*4 + j
  float4 bb[4], gg[4], be_[4];
#pragma unroll
  for (int mt = 0; mt < 4; ++mt) {
    int ob = mt * 16 + ((lane >> 4) << 2);
    bb[mt] = *(const float4*)(bp + ob);
    gg[mt] = *(const float4*)(gp + ob);
    be_[mt] = *(const float4*)(bep + ob);
  }
  const float aa = ap[0];

#pragma unroll 1
  for (int pt = 0; pt < 4; ++pt) {
    const int pfi = blockIdx.x * 16 + wid * 4 + pt;
    const ushort_t* bsrc = Ofrag + (((size_t)pfi * 2) << 9) + ((size_t)lane << 3);
    bf16x8 b0 = *(const bf16x8*)bsrc;
    bf16x8 b1 = *(const bf16x8*)(bsrc + 512);

    f32x4 acc[4];
#pragma unroll
    for (int mt = 0; mt < 4; ++mt) {
      acc[mt] = MFMA16(a[mt][0], b0, ((f32x4){0.f, 0.f, 0.f, 0.f}));
      acc[mt] = MFMA16(a[mt][1], b1, acc[mt]);
    }
    // bias + PReLU + stats
    float s1 = 0.f, s2 = 0.f;
#pragma unroll
    for (int mt = 0; mt < 4; ++mt) {
#pragma unroll
      for (int j = 0; j < 4; ++j) {
        float y = acc[mt][j] + bb[mt][j];
        y = y >= 0.f ? y : aa * y;
        acc[mt][j] = y;
        s1 += y; s2 += y * y;
      }
    }
    s1 += __shfl_xor(s1, 16); s1 += __shfl_xor(s1, 32);
    s2 += __shfl_xor(s2, 16); s2 += __shfl_xor(s2, 32);
    float mu = s1 * 0.015625f;
    float var = s2 * 0.015625f - mu * mu;
    float is = rsqrtf(var + 1e-5f);

    const int b = pfi >> 13;
    const int posl = (pfi & 8191) * 16 + (lane & 15);
    const float* xbase = x + (size_t)b * 8388608 + posl;
    float* obase = out + (size_t)b * 8388608 + posl;
#pragma unroll
    for (int mt = 0; mt < 4; ++mt) {
#pragma unroll
      for (int j = 0; j < 4; ++j) {
        int o = mt * 16 + ((lane >> 4) << 2) + j;
        float r = (acc[mt][j] - mu) * is * gg[mt][j] + be_[mt][j] + xbase[(size_t)o * 131072];
        obase[(size_t)o * 131072] = r;
      }
    }
  }
}

extern "C" void kernel_launch(void* const* d_in, const int* in_sizes, int n_in,
                              void* d_out, int out_size, void* d_ws, size_t ws_size,
                              hipStream_t stream) {
  (void)in_sizes; (void)n_in; (void)out_size; (void)ws_size;
  const float* x   = (const float*)d_in[0];
  const float* Wq  = (const float*)d_in[1];
  const float* bq  = (const float*)d_in[2];
  const float* aq  = (const float*)d_in[3];
  const float* gq  = (const float*)d_in[4];
  const float* beq = (const float*)d_in[5];
  const float* Wk  = (const float*)d_in[6];
  const float* bk  = (const float*)d_in[7];
  const float* ak  = (const float*)d_in[8];
  const float* gk  = (const float*)d_in[9];
  const float* bek = (const float*)d_in[10];
  const float* Wv  = (const float*)d_in[11];
  const float* bv  = (const float*)d_in[12];
  const float* av  = (const float*)d_in[13];
  const float* gv  = (const float*)d_in[14];
  const float* bev = (const float*)d_in[15];
  const float* Wp  = (const float*)d_in[16];
  const float* bp  = (const float*)d_in[17];
  const float* ap  = (const float*)d_in[18];
  const float* gp  = (const float*)d_in[19];
  const float* bep = (const float*)d_in[20];

  char* ws = (char*)d_ws;
  const size_t MB = 1024 * 1024;
  ushort_t* Qp    = (ushort_t*)(ws + 0 * MB);    // 8MB  [8][128][8][512]
  ushort_t* Kp    = (ushort_t*)(ws + 8 * MB);    // 8MB
  ushort_t* Vp    = (ushort_t*)(ws + 16 * MB);   // 32MB [8][64][64][512]
  ushort_t* Ofrag = (ushort_t*)(ws + 48 * MB);   // 32MB [16384 pfi][2 kf][512]

  hipFuncSetAttribute((const void*)k_attn, hipFuncAttributeMaxDynamicSharedMemorySize, 71296);

  k_proj_qkv<<<512, 512, 0, stream>>>(x, Wq, bq, aq, gq, beq, Wk, bk, ak, gk, bek,
                                      Wv, bv, av, gv, bev, Qp, Kp, Vp);
  k_attn<<<512, 512, 71296, stream>>>(Qp, Kp, Vp, Ofrag);
  k_outproj<<<1024, 256, 0, stream>>>(Ofrag, Wp, bp, ap, gp, bep, x, (float*)d_out);
}